// Round 9
// baseline (463.781 us; speedup 1.0000x reference)
//
#include <hip/hip_runtime.h>
#include <stdint.h>
#include <stddef.h>

typedef __attribute__((ext_vector_type(4))) float  f32x4;
typedef __attribute__((ext_vector_type(8))) short  s16x8;
typedef __attribute__((ext_vector_type(4))) float  float4v;
typedef __attribute__((ext_vector_type(4))) unsigned short u16x4;
typedef __attribute__((ext_vector_type(2))) unsigned int   u32x2;

#define DIM    1024
#define HEADS  16
#define HD     64
#define SEQ    2048
#define BATCH  2
#define TOKENS (BATCH * SEQ)   // 4096

// 0.125 (1/sqrt(64)) * log2(e): folded into Q so softmax uses exp2 directly
#define QSCALE 0.18033688011112042f

// ---------- helpers ----------
__device__ __forceinline__ unsigned short f2bf(float f) {
  union { float f; uint32_t u; } x; x.f = f;
  uint32_t r = x.u + 0x7fffu + ((x.u >> 16) & 1u);   // RNE
  return (unsigned short)(r >> 16);
}

__device__ __forceinline__ float fast_exp2(float x) {
#if __has_builtin(__builtin_amdgcn_exp2f)
  return __builtin_amdgcn_exp2f(x);
#else
  return exp2f(x);
#endif
}

// pack high-16s of two fp32 into one dword: (hi & 0xffff0000) | (lo >> 16)
__device__ __forceinline__ uint32_t pack_bf16_trunc(uint32_t lo, uint32_t hi) {
#if __has_builtin(__builtin_amdgcn_perm)
  return __builtin_amdgcn_perm(hi, lo, 0x07060302u);
#else
  return (hi & 0xffff0000u) | (lo >> 16);
#endif
}

// async global->LDS, 16 B per lane; lds dest = base + lane*16 (wave-uniform base)
__device__ __forceinline__ void stage16(const unsigned short* gp, unsigned short* lp) {
#if __has_builtin(__builtin_amdgcn_global_load_lds)
  __builtin_amdgcn_global_load_lds((const __attribute__((address_space(1))) void*)gp,
                                   (__attribute__((address_space(3))) void*)lp, 16, 0, 0);
#else
  *(s16x8*)(lp + (threadIdx.x & 63) * 8) = *(const s16x8*)gp;
#endif
}

// ---------- fused cast fp32 -> bf16 (x, W_qkv, W_out in one launch) ----------
#define N4_X  (TOKENS * DIM / 4)
#define N4_WQ (3 * DIM * DIM / 4)
#define N4_WO (DIM * DIM / 4)
__global__ __launch_bounds__(256) void mhsa_cast_all(const float* __restrict__ x,
    const float* __restrict__ wq, const float* __restrict__ wo,
    unsigned short* __restrict__ xb, unsigned short* __restrict__ wqb,
    unsigned short* __restrict__ wob) {
  int i = blockIdx.x * 256 + threadIdx.x;
  const float* src; unsigned short* dst; int off;
  if (i < N4_X)              { src = x;  dst = xb;  off = i; }
  else if (i < N4_X + N4_WQ) { src = wq; dst = wqb; off = i - N4_X; }
  else                       { src = wo; dst = wob; off = i - (N4_X + N4_WQ); }
  float4v f = ((const float4v*)src)[off];
  u16x4 o;
  o.x = f2bf(f.x); o.y = f2bf(f.y); o.z = f2bf(f.z); o.w = f2bf(f.w);
  ((u16x4*)dst)[off] = o;
}

// ============================================================================
// Fragment-order layouts (written by gemm_qkv, consumed by attn straight from
// global with coalesced 1KB wave b128 loads; lane l = q4*16+ln):
//  Q^F/K^F[bh][blk16][kk][l][j] = X[blk16*16+ln][kk*32+q4*8+j]   (blk16: 16 rows)
//  V^F[bh][kt][jd][kk][l][j]    = V[kt*64+kk*32+q4*8+j][jd*16+ln] (kt: 64 keys)
// ============================================================================

// ---------- QKV GEMM (operand-swapped, BK=32, dbuf, 1 barrier/iter) ----------
__global__ __launch_bounds__(256, 3) void mhsa_gemm_qkv(const unsigned short* __restrict__ A,
    const unsigned short* __restrict__ Bw, const float* __restrict__ bias,
    unsigned short* __restrict__ qws, unsigned short* __restrict__ kws,
    unsigned short* __restrict__ vws) {
  __shared__ unsigned short As[2][128 * 32];
  __shared__ unsigned short Bs[2][128 * 32];
  const int t = threadIdx.x;
  const int w = t >> 6, l = t & 63;
  const int wm = w >> 1, wn = w & 1;
  const int rowBase = blockIdx.y * 128;   // tokens
  const int colBase = blockIdx.x * 128;   // e
  const int fr = l & 15, q4 = l >> 4, ln = l & 15;
  const int srow = l >> 2;                       // staging row within slab
  const int scol = ((l & 3) ^ (srow & 3)) * 8;   // swizzled global column

  f32x4 zero = {0.f, 0.f, 0.f, 0.f};
  f32x4 acc[4][4];   // [a=e-tile][b=token-tile]
  #pragma unroll
  for (int a = 0; a < 4; ++a)
    #pragma unroll
    for (int b = 0; b < 4; ++b) acc[a][b] = zero;

  #pragma unroll
  for (int it = 0; it < 2; ++it) {
    const int c = w * 2 + it;
    stage16(A  + (size_t)(rowBase + c * 16 + srow) * DIM + scol, &As[0][c * 512]);
    stage16(Bw + (size_t)(colBase + c * 16 + srow) * DIM + scol, &Bs[0][c * 512]);
  }
  __syncthreads();

  for (int kt = 0; kt < DIM / 32; ++kt) {
    const int cur = kt & 1, nxt = cur ^ 1;
    if (kt + 1 < DIM / 32) {
      const int k1 = (kt + 1) * 32;
      #pragma unroll
      for (int it = 0; it < 2; ++it) {
        const int c = w * 2 + it;
        stage16(A  + (size_t)(rowBase + c * 16 + srow) * DIM + k1 + scol, &As[nxt][c * 512]);
        stage16(Bw + (size_t)(colBase + c * 16 + srow) * DIM + k1 + scol, &Bs[nxt][c * 512]);
      }
    }
    s16x8 xf[4], wf[4];
    #pragma unroll
    for (int b = 0; b < 4; ++b)
      xf[b] = *(const s16x8*)&As[cur][(wm * 64 + b * 16 + fr) * 32 + ((q4 ^ (fr & 3)) * 8)];
    #pragma unroll
    for (int a = 0; a < 4; ++a)
      wf[a] = *(const s16x8*)&Bs[cur][(wn * 64 + a * 16 + fr) * 32 + ((q4 ^ (fr & 3)) * 8)];
    #pragma unroll
    for (int a = 0; a < 4; ++a)
      #pragma unroll
      for (int b = 0; b < 4; ++b)
        acc[a][b] = __builtin_amdgcn_mfma_f32_16x16x32_bf16(wf[a], xf[b], acc[a][b], 0, 0, 0);
    __syncthreads();
  }

  const int which = colBase >> 10;   // 0=Q 1=K 2=V (block never straddles)
  if (which != 2) {
    // Q^F / K^F: lane holds 4 consecutive d at token n -> one 8B store each
    unsigned short* dst = (which == 0) ? qws : kws;
    const float sc = (which == 0) ? QSCALE : 1.0f;
    #pragma unroll
    for (int a = 0; a < 4; ++a) {
      const int e0 = colBase + wn * 64 + a * 16 + q4 * 4;
      const float4v bs4 = *(const float4v*)&bias[e0];
      const int h = (e0 & 1023) >> 6;
      const int kkf = a >> 1;                       // (d0>>5)
      const int q4s = ((a & 1) << 1) | (q4 >> 1);   // (d0>>3)&3
      const int jf  = (q4 & 1) * 4;                 // d0&7
      #pragma unroll
      for (int b = 0; b < 4; ++b) {
        const int tok = rowBase + wm * 64 + b * 16 + ln;
        const int bb = tok >> 11, n = tok & 2047;
        const int bhl = bb * HEADS + h;
        u16x4 pk;
        #pragma unroll
        for (int r = 0; r < 4; ++r) pk[r] = f2bf((acc[a][b][r] + bs4[r]) * sc);
        const size_t off = ((size_t)(bhl * (SEQ / 16) + (n >> 4)) * 2 + kkf) * 512
                         + q4s * 128 + ln * 8 + jf;
        *(u16x4*)&dst[off] = pk;
      }
    }
  } else {
    // V^F: lane's 4 d-values land at stride-8 slots (ln' = q4*4+r)
    #pragma unroll
    for (int a = 0; a < 4; ++a) {
      const int e0 = colBase + wn * 64 + a * 16 + q4 * 4;
      const float4v bs4 = *(const float4v*)&bias[e0];
      const int h = (e0 & 1023) >> 6;   // jd = a
      #pragma unroll
      for (int b = 0; b < 4; ++b) {
        const int tok = rowBase + wm * 64 + b * 16 + ln;
        const int bb = tok >> 11, n = tok & 2047;
        const int bhl = bb * HEADS + h;
        const int kt = n >> 6, kkf = (n >> 5) & 1, q4s = (n >> 3) & 3, jf = n & 7;
        const size_t base = ((size_t)((bhl * (SEQ / 64) + kt) * 8 + a * 2 + kkf)) * 512
                          + q4s * 128 + jf;
        #pragma unroll
        for (int r = 0; r < 4; ++r)
          vws[base + (q4 * 4 + r) * 8] = f2bf(acc[a][b][r] + bs4[r]);
      }
    }
  }
}

// ---------- Output GEMM (operand-swapped): 64x128 tiles, float4 epilogue ----------
__global__ __launch_bounds__(256, 3) void mhsa_gemm_out(const unsigned short* __restrict__ A,
    const unsigned short* __restrict__ Bw, const float* __restrict__ bias,
    float* __restrict__ out) {
  __shared__ unsigned short As[2][64 * 32];
  __shared__ unsigned short Bs[2][128 * 32];
  const int t = threadIdx.x;
  const int w = t >> 6, l = t & 63;
  const int wm = w >> 1, wn = w & 1;
  const int rowBase = blockIdx.y * 64;    // tokens (64-row tiles -> 512 blocks)
  const int colBase = blockIdx.x * 128;   // e
  const int fr = l & 15, q4 = l >> 4, ln = l & 15;
  const int srow = l >> 2;
  const int scol = ((l & 3) ^ (srow & 3)) * 8;

  f32x4 zero = {0.f, 0.f, 0.f, 0.f};
  f32x4 acc[4][2];   // [a=e-tile][b=token-tile]
  #pragma unroll
  for (int a = 0; a < 4; ++a)
    #pragma unroll
    for (int b = 0; b < 2; ++b) acc[a][b] = zero;

  #pragma unroll
  for (int it = 0; it < 3; ++it) {
    const int s = w * 3 + it;
    if (s < 4) stage16(A  + (size_t)(rowBase + s * 16 + srow) * DIM + scol, &As[0][s * 512]);
    else       stage16(Bw + (size_t)(colBase + (s - 4) * 16 + srow) * DIM + scol, &Bs[0][(s - 4) * 512]);
  }
  __syncthreads();

  for (int kt = 0; kt < DIM / 32; ++kt) {
    const int cur = kt & 1, nxt = cur ^ 1;
    if (kt + 1 < DIM / 32) {
      const int k1 = (kt + 1) * 32;
      #pragma unroll
      for (int it = 0; it < 3; ++it) {
        const int s = w * 3 + it;
        if (s < 4) stage16(A  + (size_t)(rowBase + s * 16 + srow) * DIM + k1 + scol, &As[nxt][s * 512]);
        else       stage16(Bw + (size_t)(colBase + (s - 4) * 16 + srow) * DIM + k1 + scol, &Bs[nxt][(s - 4) * 512]);
      }
    }
    s16x8 xf[2], wf[4];
    #pragma unroll
    for (int b = 0; b < 2; ++b)
      xf[b] = *(const s16x8*)&As[cur][(wm * 32 + b * 16 + fr) * 32 + ((q4 ^ (fr & 3)) * 8)];
    #pragma unroll
    for (int a = 0; a < 4; ++a)
      wf[a] = *(const s16x8*)&Bs[cur][(wn * 64 + a * 16 + fr) * 32 + ((q4 ^ (fr & 3)) * 8)];
    #pragma unroll
    for (int a = 0; a < 4; ++a)
      #pragma unroll
      for (int b = 0; b < 2; ++b)
        acc[a][b] = __builtin_amdgcn_mfma_f32_16x16x32_bf16(wf[a], xf[b], acc[a][b], 0, 0, 0);
    __syncthreads();
  }

  #pragma unroll
  for (int a = 0; a < 4; ++a) {
    const int e0 = colBase + wn * 64 + a * 16 + q4 * 4;
    const float4v bs4 = *(const float4v*)&bias[e0];
    #pragma unroll
    for (int b = 0; b < 2; ++b) {
      const int tok = rowBase + wm * 32 + b * 16 + ln;
      float4v v;
      #pragma unroll
      for (int r = 0; r < 4; ++r) v[r] = acc[a][b][r] + bs4[r];
      *(float4v*)&out[(size_t)tok * DIM + e0] = v;
    }
  }
}

// ---------- Flash attention v7: barrier-free, fragment-order global reads ----------
// 256 threads (4 waves x 32 q-rows), K/V tiles 64. NO __syncthreads anywhere:
// Q/K/V read directly from global in MFMA fragment order (coalesced 1KB wave
// b128 loads, register-double-buffered one iteration ahead -> vmcnt never
// drains; L1 broadcasts shared K/V frags across the 4 waves). LDS holds only
// the wave-private P C->A round-trip (18.4 KB/block).
// Iter jt: issue K_{jt+2}/V_{jt+1} loads -> ds_read P_jt -> S_{jt+1} MFMAs
// (cover P latency) -> PV_jt MFMAs -> exp/pack/ds_write P_{jt+1}.
__global__ __launch_bounds__(256, 2) void mhsa_attn(const unsigned short* __restrict__ qF,
    const unsigned short* __restrict__ kF, const unsigned short* __restrict__ vF,
    unsigned short* __restrict__ o) {
  __shared__ unsigned short Ps[4 * 32 * 72];    // per-wave P scratch only
  const int t = threadIdx.x, w = t >> 6, l = t & 63;
  const int q4 = l >> 4, ln = l & 15;
  const int bh = blockIdx.y, q0 = blockIdx.x * 128;
  const unsigned short* qb = qF + (size_t)bh * (SEQ * HD);
  const unsigned short* kb = kF + (size_t)bh * (SEQ * HD);
  const unsigned short* vb = vF + (size_t)bh * (SEQ * HD);
  unsigned short* Pw = &Ps[w * (32 * 72)];

  // Q fragments straight from global (rows w*32 + i*16 + ln)
  s16x8 aq[2][2];
  #pragma unroll
  for (int i = 0; i < 2; ++i)
    #pragma unroll
    for (int kk = 0; kk < 2; ++kk)
      aq[i][kk] = *(const s16x8*)&qb[((size_t)((q0 >> 4) + w * 2 + i) * 2 + kk) * 512 + l * 8];

  f32x4 zero = {0.f, 0.f, 0.f, 0.f};
  f32x4 accO[2][4];
  float lsum[2] = {0.f, 0.f};
  #pragma unroll
  for (int i = 0; i < 2; ++i)
    #pragma unroll
    for (int jd = 0; jd < 4; ++jd) accO[i][jd] = zero;

  // register double buffers: buffer consumed at iter jt is (jt&1)
  s16x8 kfr[2][4][2], vfr[2][4][2];

  // prologue: K_0 -> kfr[1] (consumed immediately); V_0 -> vfr[0]; K_1 -> kfr[0]
  #pragma unroll
  for (int jb = 0; jb < 4; ++jb)
    #pragma unroll
    for (int kk = 0; kk < 2; ++kk) {
      kfr[1][jb][kk] = *(const s16x8*)&kb[(size_t)((jb * 2 + kk)) * 512 + l * 8];
      vfr[0][jb][kk] = *(const s16x8*)&vb[(size_t)((jb * 2 + kk)) * 512 + l * 8];
      kfr[0][jb][kk] = *(const s16x8*)&kb[(size_t)(((4 + jb) * 2 + kk)) * 512 + l * 8];
    }

  // prologue compute: S_0 from kfr[1], exp, write P_0
  {
    f32x4 St[4][2];
    #pragma unroll
    for (int jb = 0; jb < 4; ++jb)
      #pragma unroll
      for (int i = 0; i < 2; ++i) St[jb][i] = zero;
    #pragma unroll
    for (int jb = 0; jb < 4; ++jb)
      #pragma unroll
      for (int i = 0; i < 2; ++i) {
        St[jb][i] = __builtin_amdgcn_mfma_f32_16x16x32_bf16(kfr[1][jb][0], aq[i][0], St[jb][i], 0, 0, 0);
        St[jb][i] = __builtin_amdgcn_mfma_f32_16x16x32_bf16(kfr[1][jb][1], aq[i][1], St[jb][i], 0, 0, 0);
      }
    #pragma unroll
    for (int i = 0; i < 2; ++i)
      #pragma unroll
      for (int jb = 0; jb < 4; ++jb) {
        uint32_t u0 = __float_as_uint(fast_exp2(St[jb][i][0]));
        uint32_t u1 = __float_as_uint(fast_exp2(St[jb][i][1]));
        uint32_t u2 = __float_as_uint(fast_exp2(St[jb][i][2]));
        uint32_t u3 = __float_as_uint(fast_exp2(St[jb][i][3]));
        lsum[i] += __uint_as_float(u0 & 0xffff0000u) + __uint_as_float(u1 & 0xffff0000u)
                 + __uint_as_float(u2 & 0xffff0000u) + __uint_as_float(u3 & 0xffff0000u);
        u32x2 pk;
        pk.x = pack_bf16_trunc(u0, u1);
        pk.y = pack_bf16_trunc(u2, u3);
        *(u32x2*)&Pw[(i * 16 + ln) * 72 + jb * 16 + q4 * 4] = pk;
      }
  }

  const int NT = SEQ / 64;   // 32
  for (int jt = 0; jt < NT; ++jt) {
    const int p = jt & 1, pn = p ^ 1;
    // issue next-iter loads: K_{jt+2} and V_{jt+1} into buffer pn (consumed at jt+1)
    if (jt + 2 < NT) {
      #pragma unroll
      for (int jb = 0; jb < 4; ++jb)
        #pragma unroll
        for (int kk = 0; kk < 2; ++kk)
          kfr[pn][jb][kk] = *(const s16x8*)&kb[(size_t)(((jt + 2) * 4 + jb) * 2 + kk) * 512 + l * 8];
    }
    if (jt + 1 < NT) {
      #pragma unroll
      for (int jb = 0; jb < 4; ++jb)
        #pragma unroll
        for (int kk = 0; kk < 2; ++kk)
          vfr[pn][jb][kk] = *(const s16x8*)&vb[(size_t)((jt + 1) * 8 + jb * 2 + kk) * 512 + l * 8];
    }

    // P_jt A-frags (written last iter; latency covered by S MFMAs below)
    s16x8 ap[2][2];
    #pragma unroll
    for (int i = 0; i < 2; ++i)
      #pragma unroll
      for (int kk = 0; kk < 2; ++kk)
        ap[i][kk] = *(const s16x8*)&Pw[(i * 16 + ln) * 72 + kk * 32 + q4 * 8];

    if (jt + 1 < NT) {
      // S_{jt+1} from kfr[p] (loaded last iter; vmcnt covers)
      f32x4 St[4][2];
      #pragma unroll
      for (int jb = 0; jb < 4; ++jb)
        #pragma unroll
        for (int i = 0; i < 2; ++i) St[jb][i] = zero;
      #pragma unroll
      for (int jb = 0; jb < 4; ++jb)
        #pragma unroll
        for (int i = 0; i < 2; ++i) {
          St[jb][i] = __builtin_amdgcn_mfma_f32_16x16x32_bf16(kfr[p][jb][0], aq[i][0], St[jb][i], 0, 0, 0);
          St[jb][i] = __builtin_amdgcn_mfma_f32_16x16x32_bf16(kfr[p][jb][1], aq[i][1], St[jb][i], 0, 0, 0);
        }

      // PV_jt
      #pragma unroll
      for (int jd = 0; jd < 4; ++jd)
        #pragma unroll
        for (int i = 0; i < 2; ++i) {
          accO[i][jd] = __builtin_amdgcn_mfma_f32_16x16x32_bf16(ap[i][0], vfr[p][jd][0], accO[i][jd], 0, 0, 0);
          accO[i][jd] = __builtin_amdgcn_mfma_f32_16x16x32_bf16(ap[i][1], vfr[p][jd][1], accO[i][jd], 0, 0, 0);
        }

      // exp -> pack -> write P_{jt+1} (after ap reads; per-wave DS order holds)
      #pragma unroll
      for (int i = 0; i < 2; ++i)
        #pragma unroll
        for (int jb = 0; jb < 4; ++jb) {
          uint32_t u0 = __float_as_uint(fast_exp2(St[jb][i][0]));
          uint32_t u1 = __float_as_uint(fast_exp2(St[jb][i][1]));
          uint32_t u2 = __float_as_uint(fast_exp2(St[jb][i][2]));
          uint32_t u3 = __float_as_uint(fast_exp2(St[jb][i][3]));
          lsum[i] += __uint_as_float(u0 & 0xffff0000u) + __uint_as_float(u1 & 0xffff0000u)
                   + __uint_as_float(u2 & 0xffff0000u) + __uint_as_float(u3 & 0xffff0000u);
          u32x2 pk;
          pk.x = pack_bf16_trunc(u0, u1);
          pk.y = pack_bf16_trunc(u2, u3);
          *(u32x2*)&Pw[(i * 16 + ln) * 72 + jb * 16 + q4 * 4] = pk;
        }
    } else {
      // last iter: only PV
      #pragma unroll
      for (int jd = 0; jd < 4; ++jd)
        #pragma unroll
        for (int i = 0; i < 2; ++i) {
          accO[i][jd] = __builtin_amdgcn_mfma_f32_16x16x32_bf16(ap[i][0], vfr[p][jd][0], accO[i][jd], 0, 0, 0);
          accO[i][jd] = __builtin_amdgcn_mfma_f32_16x16x32_bf16(ap[i][1], vfr[p][jd][1], accO[i][jd], 0, 0, 0);
        }
    }
  }

  // epilogue: cross-quad row-sum reduce, redistribute inverse, normalize, store
  const int b = bh >> 4, h = bh & 15;
  #pragma unroll
  for (int i = 0; i < 2; ++i) {
    float s = lsum[i];
    s += __shfl_xor(s, 16);
    s += __shfl_xor(s, 32);
    const float inv = 1.f / s;
    #pragma unroll
    for (int r = 0; r < 4; ++r) {
      const float invr = __shfl(inv, (l & 48) + q4 * 4 + r);
      const int row = q0 + w * 32 + i * 16 + q4 * 4 + r;
      #pragma unroll
      for (int jd = 0; jd < 4; ++jd)
        o[((size_t)(b * SEQ + row)) * DIM + h * HD + jd * 16 + ln] = f2bf(accO[i][jd][r] * invr);
    }
  }
}

// ---------- launch ----------
extern "C" void kernel_launch(void* const* d_in, const int* in_sizes, int n_in,
                              void* d_out, int out_size, void* d_ws, size_t ws_size,
                              hipStream_t stream) {
  const float* x     = (const float*)d_in[0];   // [2,2048,1024]
  const float* Wqkv  = (const float*)d_in[1];   // [3072,1024]
  const float* bqkv  = (const float*)d_in[2];   // [3072]
  const float* Wout  = (const float*)d_in[3];   // [1024,1024]
  const float* bout  = (const float*)d_in[4];   // [1024]
  float* out = (float*)d_out;

  unsigned short* ws = (unsigned short*)d_ws;
  unsigned short* x_bf    = ws;
  unsigned short* wqkv_bf = x_bf    + (size_t)TOKENS * DIM;
  unsigned short* wout_bf = wqkv_bf + (size_t)3 * DIM * DIM;
  unsigned short* q_ws    = wout_bf + (size_t)DIM * DIM;       // Q^F fragment order
  unsigned short* k_ws    = q_ws    + (size_t)TOKENS * DIM;    // K^F fragment order
  unsigned short* v_ws    = k_ws    + (size_t)TOKENS * DIM;    // V^F fragment order
  unsigned short* ao_ws   = v_ws    + (size_t)TOKENS * DIM;

  // fused cast (one launch)
  {
    const int n4 = N4_X + N4_WQ + N4_WO;   // 2,097,152 -> 8192 blocks
    mhsa_cast_all<<<n4 / 256, 256, 0, stream>>>(x, Wqkv, Wout, x_bf, wqkv_bf, wout_bf);
  }

  // QKV projection + fragment-order scatter (Q pre-scaled)
  {
    dim3 grid(3 * DIM / 128, TOKENS / 128);   // (24, 32) = 768 blocks = 3/CU, one round
    mhsa_gemm_qkv<<<grid, 256, 0, stream>>>(x_bf, wqkv_bf, bqkv, q_ws, k_ws, v_ws);
  }

  // fused attention (barrier-free)
  {
    dim3 grid(SEQ / 128, BATCH * HEADS);      // (16, 32), 256 threads
    mhsa_attn<<<grid, 256, 0, stream>>>(q_ws, k_ws, v_ws, ao_ws);
  }

  // output projection
  {
    dim3 grid(DIM / 128, TOKENS / 64);        // (8, 64) = 512 blocks
    mhsa_gemm_out<<<grid, 256, 0, stream>>>(ao_ws, wout_bf, bout, out);
  }
}